// Round 2
// baseline (1199.430 us; speedup 1.0000x reference)
//
#include <hip/hip_runtime.h>
#include <cstddef>

// Problem dims
#define BATCH 64
#define SEQ   256
#define VOCAB 50000
#define DIM   300
#define NW    8192
#define CLEN  16
#define CDIM  30
#define CHC   30
#define HID   128
#define NT    17
#define IN0   (DIM + CHC)   // 330
#define IN0P  336           // padded to multiple of 16
#define IN1   (2 * HID)     // 256
#define NPOS  (BATCH * SEQ) // 16384

// Workspace layout (floats)
constexpr size_t SZ_XG    = 2ull * BATCH * SEQ * 384;    // 12,582,912
constexpr size_t SZ_TEXTS = (size_t)NPOS * IN0P;         // 5,505,024 (aliased as h0 after GEMM0)
constexpr size_t SZ_H1    = (size_t)NPOS * 256;          // 4,194,304
constexpr size_t SZ_TOK   = 245792;                      // (NW+1)*30 rounded
constexpr size_t SZ_EMIS  = (size_t)NPOS * NT;           // 278,528
constexpr size_t SZ_WPAD  = 768ull * IN0P;               // 258,048
constexpr size_t OFF_XG    = 0;
constexpr size_t OFF_TEXTS = OFF_XG + SZ_XG;
constexpr size_t OFF_H1    = OFF_TEXTS + SZ_TEXTS;
constexpr size_t OFF_TOK   = OFF_H1 + SZ_H1;
constexpr size_t OFF_EMIS  = OFF_TOK + SZ_TOK;
constexpr size_t OFF_WPAD  = OFF_EMIS + SZ_EMIS;
constexpr size_t OFF_LLH   = OFF_WPAD + SZ_WPAD;

__device__ __forceinline__ float sigm(float x) {
    return 1.f / (1.f + __expf(-x));
}
__device__ __forceinline__ float tanh_fast(float x) {
    x = fminf(fmaxf(x, -15.f), 15.f);
    float e = __expf(-2.f * x);
    return (1.f - e) / (1.f + e);
}

// ---------------- K1: char CNN + relu + maxpool -> tok_enc[(n+1)][30] ----
__global__ __launch_bounds__(256) void char_conv_k(
    const float* __restrict__ char_emb,  // [500][30]
    const float* __restrict__ conv_w,    // [30][30][3]
    const float* __restrict__ conv_b,    // [30]
    const int*   __restrict__ words,     // [8192][16]
    float* __restrict__ tok_enc)         // [8193][30]
{
    __shared__ __align__(16) float cs[8][CLEN][CDIM];
    __shared__ float wsm[CHC * CDIM * 3];
    __shared__ float bs[CHC];
    int n0 = blockIdx.x * 8;
    int tid = threadIdx.x;
    for (int e = tid; e < CHC * CDIM * 3; e += 256) wsm[e] = conv_w[e];
    if (tid < CHC) bs[tid] = conv_b[tid];
    for (int e = tid; e < 8 * CLEN * CDIM; e += 256) {
        int wi = e / (CLEN * CDIM);
        int rem = e - wi * (CLEN * CDIM);
        int l = rem / CDIM;
        int i = rem - l * CDIM;
        int ci = words[(n0 + wi) * CLEN + l];
        cs[wi][l][i] = char_emb[ci * CDIM + i];
    }
    __syncthreads();
    int wi = tid >> 5;
    int o = tid & 31;
    if (o < CHC) {
        float best = -1e30f;
        for (int l = 0; l < CLEN; l++) {
            float s = 0.f;
            #pragma unroll
            for (int k = 0; k < 3; k++) {
                int ll = l + k - 1;
                if (ll >= 0 && ll < CLEN) {
                    #pragma unroll
                    for (int i = 0; i < CDIM; i++)
                        s += cs[wi][ll][i] * wsm[(o * CDIM + i) * 3 + k];
                }
            }
            best = fmaxf(best, s);
        }
        tok_enc[(size_t)(n0 + wi + 1) * CDIM + o] = fmaxf(best + bs[o], 0.f);
    }
}

// ---------------- K2: texts = concat(word_emb[tok], tok_enc[widx]), pad to 336
__global__ __launch_bounds__(128) void build_texts_k(
    const float* __restrict__ word_emb,
    const float* __restrict__ tok_enc,
    const int*   __restrict__ tokens,
    const int*   __restrict__ widx,
    float* __restrict__ texts)
{
    int p = blockIdx.x;
    int tok = tokens[p];
    int ci = widx[p];
    float* o = texts + (size_t)p * IN0P;
    const float* wr = word_emb + (size_t)tok * DIM;
    const float* tr = tok_enc + (size_t)ci * CDIM;
    for (int c = threadIdx.x; c < IN0P; c += 128)
        o[c] = (c < DIM) ? wr[c] : (c < IN0 ? tr[c - DIM] : 0.f);
}

// ---------------- K2b: pad w_ih_l0 (768x330) -> (768x336) ---------------
__global__ __launch_bounds__(64) void pad_w_k(
    const float* __restrict__ w, float* __restrict__ wp)
{
    int r = blockIdx.x;
    for (int c = threadIdx.x; c < IN0P; c += 64)
        wp[(size_t)r * IN0P + c] = (c < IN0) ? w[(size_t)r * IN0 + c] : 0.f;
}

// ---------------- K3/K5: xg = A @ W_ih^T + b_ih, stored [d][b][t][g] -----
// A: [16384][K] row-major (K multiple of 16), W: [768][K] row-major
#define GBM 128
#define GBN 128
#define GBK 16
__global__ __launch_bounds__(256) void gemm_xg_k(
    const float* __restrict__ A,
    const float* __restrict__ W,
    const float* __restrict__ bias,
    float* __restrict__ out,
    int K)
{
    __shared__ __align__(16) float As[GBK][GBM];
    __shared__ __align__(16) float Ws[GBK][GBN];
    int tid = threadIdx.x;
    int m0 = blockIdx.x * GBM;
    int n0 = blockIdx.y * GBN;
    int lrow = tid >> 1;
    int lk = (tid & 1) * 8;
    int ty = tid >> 4;   // 0..15 (m)
    int tx = tid & 15;   // 0..15 (n)

    float acc[8][8];
    #pragma unroll
    for (int i = 0; i < 8; i++)
        #pragma unroll
        for (int j = 0; j < 8; j++) acc[i][j] = 0.f;

    for (int k0 = 0; k0 < K; k0 += GBK) {
        const float4* ap = (const float4*)(A + (size_t)(m0 + lrow) * K + k0 + lk);
        const float4* wp = (const float4*)(W + (size_t)(n0 + lrow) * K + k0 + lk);
        float4 va0 = ap[0], va1 = ap[1];
        float4 vw0 = wp[0], vw1 = wp[1];
        As[lk + 0][lrow] = va0.x; As[lk + 1][lrow] = va0.y;
        As[lk + 2][lrow] = va0.z; As[lk + 3][lrow] = va0.w;
        As[lk + 4][lrow] = va1.x; As[lk + 5][lrow] = va1.y;
        As[lk + 6][lrow] = va1.z; As[lk + 7][lrow] = va1.w;
        Ws[lk + 0][lrow] = vw0.x; Ws[lk + 1][lrow] = vw0.y;
        Ws[lk + 2][lrow] = vw0.z; Ws[lk + 3][lrow] = vw0.w;
        Ws[lk + 4][lrow] = vw1.x; Ws[lk + 5][lrow] = vw1.y;
        Ws[lk + 6][lrow] = vw1.z; Ws[lk + 7][lrow] = vw1.w;
        __syncthreads();
        #pragma unroll
        for (int k = 0; k < GBK; k++) {
            float4 a0 = *(const float4*)&As[k][ty * 8];
            float4 a1 = *(const float4*)&As[k][ty * 8 + 4];
            float4 b0 = *(const float4*)&Ws[k][tx * 8];
            float4 b1 = *(const float4*)&Ws[k][tx * 8 + 4];
            float av[8] = {a0.x, a0.y, a0.z, a0.w, a1.x, a1.y, a1.z, a1.w};
            float bv[8] = {b0.x, b0.y, b0.z, b0.w, b1.x, b1.y, b1.z, b1.w};
            #pragma unroll
            for (int i = 0; i < 8; i++)
                #pragma unroll
                for (int j = 0; j < 8; j++)
                    acc[i][j] += av[i] * bv[j];
        }
        __syncthreads();
    }
    // store to xg layout: ((d*64+b)*256+t)*384 + g
    int nb = n0 + tx * 8;
    int d = nb / 384;
    int g0 = nb - d * 384;
    float bvv[8];
    #pragma unroll
    for (int j = 0; j < 8; j++) bvv[j] = bias[nb + j];
    int mbase = m0 + ty * 8;
    #pragma unroll
    for (int i = 0; i < 8; i++) {
        int m = mbase + i;
        int b = m >> 8;
        int t = m & 255;
        float* op = out + (((size_t)(d * BATCH + b) * SEQ + t) * 384 + g0);
        #pragma unroll
        for (int j = 0; j < 8; j++) op[j] = acc[i][j] + bvv[j];
    }
}

// ---------------- K4/K6: GRU recurrence, one wg per (dir, batch) ---------
// 192 threads; thread i owns weight rows i and i+192 (2x128 = 256 VGPRs).
// Rows <256 are r/z gates -> srz[row]; rows >=256 are n-gates, owned by
// threads i>=64 (j = i-64) which do the h update. xg has b_ih folded;
// b_hh added here (the n-gate needs it inside r*hn).
__global__ __launch_bounds__(192, 1) void gru_rec_k(
    const float* __restrict__ xg,    // [2][64][256][384]
    const float* __restrict__ w_hh,  // [2][384][128]
    const float* __restrict__ b_hh,  // [2][384]
    const int*   __restrict__ lens,  // [64]
    float* __restrict__ out)         // [64][256][256], channel = d*128+j
{
    int d = blockIdx.x & 1;
    int b = blockIdx.x >> 1;
    int i = threadIdx.x;       // 0..191
    int row0 = i;              // < 256 always (r or z gate)
    int row1 = i + 192;        // z gate if i<64, n gate if i>=64
    __shared__ __align__(16) float h[HID];
    __shared__ float srz[256];

    float4 w0[32], w1[32];
    {
        const float4* wr0 = (const float4*)(w_hh + ((size_t)d * 384 + row0) * HID);
        const float4* wr1 = (const float4*)(w_hh + ((size_t)d * 384 + row1) * HID);
        #pragma unroll
        for (int q = 0; q < 32; q++) { w0[q] = wr0[q]; w1[q] = wr1[q]; }
    }
    float bh0 = b_hh[d * 384 + row0];
    float bh1 = b_hh[d * 384 + row1];
    int len = lens[b];

    if (i < HID) h[i] = 0.f;
    __syncthreads();

    const float* xgb = xg + ((size_t)(d * BATCH + b)) * SEQ * 384;
    float* outb = out + (size_t)b * SEQ * 256 + d * HID;

    int t0 = d ? (SEQ - 1) : 0;
    float pxv0 = xgb[(size_t)t0 * 384 + row0];
    float pxv1 = xgb[(size_t)t0 * 384 + row1];

    for (int s = 0; s < SEQ; s++) {
        int t = d ? (SEQ - 1 - s) : s;
        float xv0 = pxv0, xv1 = pxv1;
        // prefetch next step's xg (off the critical path)
        int sn = (s + 1 < SEQ) ? (s + 1) : s;
        int tn = d ? (SEQ - 1 - sn) : sn;
        pxv0 = xgb[(size_t)tn * 384 + row0];
        pxv1 = xgb[(size_t)tn * 384 + row1];

        const float4* h4 = (const float4*)h;
        float a0x = 0.f, a0y = 0.f, a0z = 0.f, a0w = 0.f;
        float a1x = 0.f, a1y = 0.f, a1z = 0.f, a1w = 0.f;
        #pragma unroll
        for (int q = 0; q < 32; q++) {
            float4 hv = h4[q];
            a0x += w0[q].x * hv.x; a0y += w0[q].y * hv.y;
            a0z += w0[q].z * hv.z; a0w += w0[q].w * hv.w;
            a1x += w1[q].x * hv.x; a1y += w1[q].y * hv.y;
            a1z += w1[q].z * hv.z; a1w += w1[q].w * hv.w;
        }
        float acc0 = bh0 + ((a0x + a0y) + (a0z + a0w));
        float acc1 = bh1 + ((a1x + a1y) + (a1z + a1w));

        srz[row0] = sigm(xv0 + acc0);
        if (row1 < 256) srz[row1] = sigm(xv1 + acc1);
        __syncthreads();
        if (i >= 64) {
            int j = i - 64;
            float r = srz[j];
            float z = srz[HID + j];
            float n = tanh_fast(xv1 + r * acc1);
            float hold = h[j];
            float hnew = (1.f - z) * n + z * hold;
            float hv = (t < len) ? hnew : hold;
            h[j] = hv;
            outb[(size_t)t * 256 + j] = hv;
        }
        __syncthreads();
    }
}

// ---------------- K7: MLP (relu) + emissions -----------------------------
__global__ __launch_bounds__(128) void mlp_emis_k(
    const float* __restrict__ h1,    // [16384][256]
    const float* __restrict__ w1,    // [256][128]
    const float* __restrict__ b1,    // [128]
    const float* __restrict__ w2,    // [128][17]
    const float* __restrict__ b2,    // [17]
    float* __restrict__ emis)        // [16384][17]
{
    __shared__ __align__(16) float hrow[8 * 256];
    __shared__ float hid[8][HID];
    int p0 = blockIdx.x * 8;
    int tid = threadIdx.x;
    for (int e = tid; e < 8 * 256; e += 128)
        hrow[e] = h1[(size_t)p0 * 256 + e];
    __syncthreads();
    float acc[8];
    float bb = b1[tid];
    #pragma unroll
    for (int i = 0; i < 8; i++) acc[i] = bb;
    for (int k = 0; k < 256; k++) {
        float wv = w1[k * HID + tid];
        #pragma unroll
        for (int i = 0; i < 8; i++) acc[i] += hrow[i * 256 + k] * wv;
    }
    #pragma unroll
    for (int i = 0; i < 8; i++) hid[i][tid] = fmaxf(acc[i], 0.f);
    __syncthreads();
    for (int idx = tid; idx < 8 * NT; idx += 128) {
        int pos = idx / NT;
        int tg = idx - pos * NT;
        float a = b2[tg];
        for (int k = 0; k < HID; k++) a += hid[pos][k] * w2[k * NT + tg];
        emis[(size_t)(p0 + pos) * NT + tg] = a;
    }
}

// ---------------- K8: CRF score + forward algorithm ----------------------
__global__ __launch_bounds__(64) void crf_k(
    const float* __restrict__ emis,   // [64][256][17]
    const float* __restrict__ start,
    const float* __restrict__ endv,
    const float* __restrict__ trans,  // [17][17]
    const int*   __restrict__ target, // [64][256]
    const int*   __restrict__ lens,
    float* __restrict__ llh)          // [64]
{
    int b = blockIdx.x;
    int tid = threadIdx.x;
    __shared__ float tr[NT * NT];
    __shared__ float aSh[NT];
    __shared__ float scoreSh;
    for (int e = tid; e < NT * NT; e += 64) tr[e] = trans[e];
    __syncthreads();
    int len = lens[b];
    const int* tgt = target + b * SEQ;
    const float* eb = emis + (size_t)b * SEQ * NT;

    // gold score (parallel over t, reduce in-wave)
    float part = 0.f;
    for (int t = 1 + tid; t < SEQ; t += 64) {
        if (t < len) {
            int tp = tgt[t - 1], tc = tgt[t];
            part += tr[tp * NT + tc] + eb[(size_t)t * NT + tc];
        }
    }
    #pragma unroll
    for (int off = 32; off > 0; off >>= 1)
        part += __shfl_down(part, off, 64);
    if (tid == 0) {
        int t0 = tgt[0];
        scoreSh = part + start[t0] + eb[t0] + endv[tgt[len - 1]];
    }

    // forward algorithm
    float a = (tid < NT) ? (start[tid] + eb[tid]) : 0.f;
    for (int t = 1; t < SEQ; t++) {
        if (tid < NT) aSh[tid] = a;
        __syncthreads();
        if (t < len && tid < NT) {
            float m = -1e30f;
            #pragma unroll
            for (int i = 0; i < NT; i++)
                m = fmaxf(m, aSh[i] + tr[i * NT + tid]);
            float ssum = 0.f;
            #pragma unroll
            for (int i = 0; i < NT; i++)
                ssum += __expf(aSh[i] + tr[i * NT + tid] - m);
            a = m + __logf(ssum) + eb[(size_t)t * NT + tid];
        }
        __syncthreads();
    }
    float v = (tid < NT) ? (a + endv[tid]) : -1e30f;
    float m = v;
    #pragma unroll
    for (int off = 32; off > 0; off >>= 1)
        m = fmaxf(m, __shfl_down(m, off, 64));
    m = __shfl(m, 0, 64);
    float e = (tid < NT) ? __expf(v - m) : 0.f;
    #pragma unroll
    for (int off = 32; off > 0; off >>= 1)
        e += __shfl_down(e, off, 64);
    if (tid == 0) {
        float logz = m + __logf(e);
        llh[b] = scoreSh - logz;
    }
}

// ---------------- K9: final loss -----------------------------------------
__global__ __launch_bounds__(64) void finalize_k(
    const float* __restrict__ llh,
    const int*   __restrict__ lens,
    float* __restrict__ out)
{
    int tid = threadIdx.x;
    float s = llh[tid];
    float lf = (float)lens[tid];
    #pragma unroll
    for (int off = 32; off > 0; off >>= 1) {
        s += __shfl_down(s, off, 64);
        lf += __shfl_down(lf, off, 64);
    }
    if (tid == 0) out[0] = -(s / lf);
}

extern "C" void kernel_launch(void* const* d_in, const int* in_sizes, int n_in,
                              void* d_out, int out_size, void* d_ws, size_t ws_size,
                              hipStream_t stream) {
    const float* char_emb = (const float*)d_in[0];
    const float* conv_w   = (const float*)d_in[1];
    const float* conv_b   = (const float*)d_in[2];
    const float* word_emb = (const float*)d_in[3];
    const float* w_ih_l0  = (const float*)d_in[4];
    const float* w_hh_l0  = (const float*)d_in[5];
    const float* b_ih_l0  = (const float*)d_in[6];
    const float* b_hh_l0  = (const float*)d_in[7];
    const float* w_ih_l1  = (const float*)d_in[8];
    const float* w_hh_l1  = (const float*)d_in[9];
    const float* b_ih_l1  = (const float*)d_in[10];
    const float* b_hh_l1  = (const float*)d_in[11];
    const float* mlp_w1   = (const float*)d_in[12];
    const float* mlp_b1   = (const float*)d_in[13];
    const float* mlp_w2   = (const float*)d_in[14];
    const float* mlp_b2   = (const float*)d_in[15];
    const float* crf_start= (const float*)d_in[16];
    const float* crf_end  = (const float*)d_in[17];
    const float* crf_trans= (const float*)d_in[18];
    const int* bcw   = (const int*)d_in[19];
    // d_in[20] batched_char_words_len: unused by reference
    const int* bcwi  = (const int*)d_in[21];
    const int* btok  = (const int*)d_in[22];
    const int* blen  = (const int*)d_in[23];
    const int* target= (const int*)d_in[24];

    float* ws    = (float*)d_ws;
    float* xg    = ws + OFF_XG;
    float* texts = ws + OFF_TEXTS;   // aliased: h0 overwrites texts after xg0 GEMM
    float* h0    = texts;
    float* h1    = ws + OFF_H1;
    float* tok   = ws + OFF_TOK;
    float* emis  = ws + OFF_EMIS;
    float* wpad  = ws + OFF_WPAD;
    float* llh   = ws + OFF_LLH;

    hipMemsetAsync(tok, 0, CDIM * sizeof(float), stream);  // tok_enc row 0 = zeros
    pad_w_k<<<768, 64, 0, stream>>>(w_ih_l0, wpad);
    char_conv_k<<<NW / 8, 256, 0, stream>>>(char_emb, conv_w, conv_b, bcw, tok);
    build_texts_k<<<NPOS, 128, 0, stream>>>(word_emb, tok, btok, bcwi, texts);
    gemm_xg_k<<<dim3(NPOS / GBM, 768 / GBN), 256, 0, stream>>>(texts, wpad, b_ih_l0, xg, IN0P);
    gru_rec_k<<<2 * BATCH, 192, 0, stream>>>(xg, w_hh_l0, b_hh_l0, blen, h0);
    gemm_xg_k<<<dim3(NPOS / GBM, 768 / GBN), 256, 0, stream>>>(h0, w_ih_l1, b_ih_l1, xg, IN1);
    gru_rec_k<<<2 * BATCH, 192, 0, stream>>>(xg, w_hh_l1, b_hh_l1, blen, h1);
    mlp_emis_k<<<NPOS / 8, 128, 0, stream>>>(h1, mlp_w1, mlp_b1, mlp_w2, mlp_b2, emis);
    crf_k<<<BATCH, 64, 0, stream>>>(emis, crf_start, crf_end, crf_trans, target, blen, llh);
    finalize_k<<<1, 64, 0, stream>>>(llh, blen, (float*)d_out);
}

// Round 3
// 1054.748 us; speedup vs baseline: 1.1372x; 1.1372x over previous
//
#include <hip/hip_runtime.h>
#include <cstddef>

// Problem dims
#define BATCH 64
#define SEQ   256
#define VOCAB 50000
#define DIM   300
#define NW    8192
#define CLEN  16
#define CDIM  30
#define CHC   30
#define HID   128
#define NT    17
#define IN0   (DIM + CHC)   // 330
#define IN0P  336           // padded to multiple of 16
#define IN1   (2 * HID)     // 256
#define NPOS  (BATCH * SEQ) // 16384

// Workspace layout (floats)
constexpr size_t SZ_XG    = 2ull * BATCH * SEQ * 384;    // 12,582,912
constexpr size_t SZ_TEXTS = (size_t)NPOS * IN0P;         // 5,505,024 (aliased as h0 after GEMM0)
constexpr size_t SZ_H1    = (size_t)NPOS * 256;          // 4,194,304
constexpr size_t SZ_TOK   = 245792;                      // (NW+1)*30 rounded
constexpr size_t SZ_EMIS  = (size_t)NPOS * NT;           // 278,528
constexpr size_t SZ_WPAD  = 768ull * IN0P;               // 258,048
constexpr size_t OFF_XG    = 0;
constexpr size_t OFF_TEXTS = OFF_XG + SZ_XG;
constexpr size_t OFF_H1    = OFF_TEXTS + SZ_TEXTS;
constexpr size_t OFF_TOK   = OFF_H1 + SZ_H1;
constexpr size_t OFF_EMIS  = OFF_TOK + SZ_TOK;
constexpr size_t OFF_WPAD  = OFF_EMIS + SZ_EMIS;
constexpr size_t OFF_LLH   = OFF_WPAD + SZ_WPAD;

__device__ __forceinline__ float sigm(float x) {
    return 1.f / (1.f + __expf(-x));
}
__device__ __forceinline__ float tanh_fast(float x) {
    x = fminf(fmaxf(x, -15.f), 15.f);
    float e = __expf(-2.f * x);
    return (1.f - e) / (1.f + e);
}

// ---------------- K1: char CNN + relu + maxpool -> tok_enc[(n+1)][30] ----
__global__ __launch_bounds__(256) void char_conv_k(
    const float* __restrict__ char_emb,  // [500][30]
    const float* __restrict__ conv_w,    // [30][30][3]
    const float* __restrict__ conv_b,    // [30]
    const int*   __restrict__ words,     // [8192][16]
    float* __restrict__ tok_enc)         // [8193][30]
{
    __shared__ __align__(16) float cs[8][CLEN][CDIM];
    __shared__ float wsm[CHC * CDIM * 3];
    __shared__ float bs[CHC];
    int n0 = blockIdx.x * 8;
    int tid = threadIdx.x;
    for (int e = tid; e < CHC * CDIM * 3; e += 256) wsm[e] = conv_w[e];
    if (tid < CHC) bs[tid] = conv_b[tid];
    for (int e = tid; e < 8 * CLEN * CDIM; e += 256) {
        int wi = e / (CLEN * CDIM);
        int rem = e - wi * (CLEN * CDIM);
        int l = rem / CDIM;
        int i = rem - l * CDIM;
        int ci = words[(n0 + wi) * CLEN + l];
        cs[wi][l][i] = char_emb[ci * CDIM + i];
    }
    __syncthreads();
    int wi = tid >> 5;
    int o = tid & 31;
    if (o < CHC) {
        float best = -1e30f;
        for (int l = 0; l < CLEN; l++) {
            float s = 0.f;
            #pragma unroll
            for (int k = 0; k < 3; k++) {
                int ll = l + k - 1;
                if (ll >= 0 && ll < CLEN) {
                    #pragma unroll
                    for (int i = 0; i < CDIM; i++)
                        s += cs[wi][ll][i] * wsm[(o * CDIM + i) * 3 + k];
                }
            }
            best = fmaxf(best, s);
        }
        tok_enc[(size_t)(n0 + wi + 1) * CDIM + o] = fmaxf(best + bs[o], 0.f);
    }
}

// ---------------- K2: texts = concat(word_emb[tok], tok_enc[widx]), pad to 336
__global__ __launch_bounds__(128) void build_texts_k(
    const float* __restrict__ word_emb,
    const float* __restrict__ tok_enc,
    const int*   __restrict__ tokens,
    const int*   __restrict__ widx,
    float* __restrict__ texts)
{
    int p = blockIdx.x;
    int tok = tokens[p];
    int ci = widx[p];
    float* o = texts + (size_t)p * IN0P;
    const float* wr = word_emb + (size_t)tok * DIM;
    const float* tr = tok_enc + (size_t)ci * CDIM;
    for (int c = threadIdx.x; c < IN0P; c += 128)
        o[c] = (c < DIM) ? wr[c] : (c < IN0 ? tr[c - DIM] : 0.f);
}

// ---------------- K2b: pad w_ih_l0 (768x330) -> (768x336) ---------------
__global__ __launch_bounds__(64) void pad_w_k(
    const float* __restrict__ w, float* __restrict__ wp)
{
    int r = blockIdx.x;
    for (int c = threadIdx.x; c < IN0P; c += 64)
        wp[(size_t)r * IN0P + c] = (c < IN0) ? w[(size_t)r * IN0 + c] : 0.f;
}

// ---------------- K3/K5: xg = A @ W_ih^T + b_ih, stored [d][b][t][g] -----
// A: [16384][K] row-major (K multiple of 16), W: [768][K] row-major
#define GBM 128
#define GBN 128
#define GBK 16
__global__ __launch_bounds__(256) void gemm_xg_k(
    const float* __restrict__ A,
    const float* __restrict__ W,
    const float* __restrict__ bias,
    float* __restrict__ out,
    int K)
{
    __shared__ __align__(16) float As[GBK][GBM];
    __shared__ __align__(16) float Ws[GBK][GBN];
    int tid = threadIdx.x;
    int m0 = blockIdx.x * GBM;
    int n0 = blockIdx.y * GBN;
    int lrow = tid >> 1;
    int lk = (tid & 1) * 8;
    int ty = tid >> 4;   // 0..15 (m)
    int tx = tid & 15;   // 0..15 (n)

    float acc[8][8];
    #pragma unroll
    for (int i = 0; i < 8; i++)
        #pragma unroll
        for (int j = 0; j < 8; j++) acc[i][j] = 0.f;

    for (int k0 = 0; k0 < K; k0 += GBK) {
        const float4* ap = (const float4*)(A + (size_t)(m0 + lrow) * K + k0 + lk);
        const float4* wp = (const float4*)(W + (size_t)(n0 + lrow) * K + k0 + lk);
        float4 va0 = ap[0], va1 = ap[1];
        float4 vw0 = wp[0], vw1 = wp[1];
        As[lk + 0][lrow] = va0.x; As[lk + 1][lrow] = va0.y;
        As[lk + 2][lrow] = va0.z; As[lk + 3][lrow] = va0.w;
        As[lk + 4][lrow] = va1.x; As[lk + 5][lrow] = va1.y;
        As[lk + 6][lrow] = va1.z; As[lk + 7][lrow] = va1.w;
        Ws[lk + 0][lrow] = vw0.x; Ws[lk + 1][lrow] = vw0.y;
        Ws[lk + 2][lrow] = vw0.z; Ws[lk + 3][lrow] = vw0.w;
        Ws[lk + 4][lrow] = vw1.x; Ws[lk + 5][lrow] = vw1.y;
        Ws[lk + 6][lrow] = vw1.z; Ws[lk + 7][lrow] = vw1.w;
        __syncthreads();
        #pragma unroll
        for (int k = 0; k < GBK; k++) {
            float4 a0 = *(const float4*)&As[k][ty * 8];
            float4 a1 = *(const float4*)&As[k][ty * 8 + 4];
            float4 b0 = *(const float4*)&Ws[k][tx * 8];
            float4 b1 = *(const float4*)&Ws[k][tx * 8 + 4];
            float av[8] = {a0.x, a0.y, a0.z, a0.w, a1.x, a1.y, a1.z, a1.w};
            float bv[8] = {b0.x, b0.y, b0.z, b0.w, b1.x, b1.y, b1.z, b1.w};
            #pragma unroll
            for (int i = 0; i < 8; i++)
                #pragma unroll
                for (int j = 0; j < 8; j++)
                    acc[i][j] += av[i] * bv[j];
        }
        __syncthreads();
    }
    // store to xg layout: ((d*64+b)*256+t)*384 + g
    int nb = n0 + tx * 8;
    int d = nb / 384;
    int g0 = nb - d * 384;
    float bvv[8];
    #pragma unroll
    for (int j = 0; j < 8; j++) bvv[j] = bias[nb + j];
    int mbase = m0 + ty * 8;
    #pragma unroll
    for (int i = 0; i < 8; i++) {
        int m = mbase + i;
        int b = m >> 8;
        int t = m & 255;
        float* op = out + (((size_t)(d * BATCH + b) * SEQ + t) * 384 + g0);
        #pragma unroll
        for (int j = 0; j < 8; j++) op[j] = acc[i][j] + bvv[j];
    }
}

// ---------------- K4/K6: GRU recurrence, one wg per (dir, batch) ---------
// 512 threads: thread (e = i>>2, c = i&3) owns gate rows {e, 128+e, 256+e}
// restricted to k-chunk [32c, 32c+32). 24 float4 weights stay in VGPRs.
// Partial dots reduced across the 4 adjacent lanes via __shfl_xor (same
// wave). h double-buffered in LDS -> ONE barrier per step. hold (h[e])
// carried in registers. xg has b_ih folded; b_hh added here.
__global__ __launch_bounds__(512, 1) void gru_rec_k(
    const float* __restrict__ xg,    // [2][64][256][384]
    const float* __restrict__ w_hh,  // [2][384][128]
    const float* __restrict__ b_hh,  // [2][384]
    const int*   __restrict__ lens,  // [64]
    float* __restrict__ out)         // [64][256][256], channel = d*128+j
{
    int d = blockIdx.x & 1;
    int b = blockIdx.x >> 1;
    int i = threadIdx.x;   // 0..511
    int e = i >> 2;        // 0..127
    int c = i & 3;         // 0..3
    __shared__ __align__(16) float hS[2 * HID];

    int rR = e, rZ = HID + e, rN = 2 * HID + e;
    const float* wbase = w_hh + (size_t)d * 384 * HID;
    float4 wR[8], wZ[8], wN[8];
    {
        const float4* pR = (const float4*)(wbase + (size_t)rR * HID + 32 * c);
        const float4* pZ = (const float4*)(wbase + (size_t)rZ * HID + 32 * c);
        const float4* pN = (const float4*)(wbase + (size_t)rN * HID + 32 * c);
        #pragma unroll
        for (int q = 0; q < 8; q++) { wR[q] = pR[q]; wZ[q] = pZ[q]; wN[q] = pN[q]; }
    }
    float bhR = b_hh[d * 384 + rR];
    float bhZ = b_hh[d * 384 + rZ];
    float bhN = b_hh[d * 384 + rN];
    int len = lens[b];

    if (i < HID) hS[i] = 0.f;
    float hold = 0.f;
    __syncthreads();

    const float* xgb = xg + ((size_t)(d * BATCH + b)) * SEQ * 384;
    float* outb = out + (size_t)b * SEQ * 256 + d * HID;

    int t0 = d ? (SEQ - 1) : 0;
    float xvR = xgb[(size_t)t0 * 384 + rR];
    float xvZ = xgb[(size_t)t0 * 384 + rZ];
    float xvN = xgb[(size_t)t0 * 384 + rN];

    for (int s = 0; s < SEQ; s++) {
        int t = d ? (SEQ - 1 - s) : s;
        // prefetch next step's xg (off the critical path)
        int sn = (s + 1 < SEQ) ? (s + 1) : s;
        int tn = d ? (SEQ - 1 - sn) : sn;
        float nxvR = xgb[(size_t)tn * 384 + rR];
        float nxvZ = xgb[(size_t)tn * 384 + rZ];
        float nxvN = xgb[(size_t)tn * 384 + rN];

        const float4* h4 = (const float4*)(hS + (s & 1) * HID) + c * 8;
        float sR0 = 0.f, sR1 = 0.f, sZ0 = 0.f, sZ1 = 0.f, sN0 = 0.f, sN1 = 0.f;
        #pragma unroll
        for (int q = 0; q < 4; q++) {
            float4 x = h4[q];
            sR0 += wR[q].x * x.x + wR[q].y * x.y + wR[q].z * x.z + wR[q].w * x.w;
            sZ0 += wZ[q].x * x.x + wZ[q].y * x.y + wZ[q].z * x.z + wZ[q].w * x.w;
            sN0 += wN[q].x * x.x + wN[q].y * x.y + wN[q].z * x.z + wN[q].w * x.w;
        }
        #pragma unroll
        for (int q = 4; q < 8; q++) {
            float4 x = h4[q];
            sR1 += wR[q].x * x.x + wR[q].y * x.y + wR[q].z * x.z + wR[q].w * x.w;
            sZ1 += wZ[q].x * x.x + wZ[q].y * x.y + wZ[q].z * x.z + wZ[q].w * x.w;
            sN1 += wN[q].x * x.x + wN[q].y * x.y + wN[q].z * x.z + wN[q].w * x.w;
        }
        float sR = sR0 + sR1, sZ = sZ0 + sZ1, sN = sN0 + sN1;
        sR += __shfl_xor(sR, 1, 64); sR += __shfl_xor(sR, 2, 64);
        sZ += __shfl_xor(sZ, 1, 64); sZ += __shfl_xor(sZ, 2, 64);
        sN += __shfl_xor(sN, 1, 64); sN += __shfl_xor(sN, 2, 64);

        float r = sigm(xvR + sR + bhR);
        float z = sigm(xvZ + sZ + bhZ);
        float n = tanh_fast(xvN + r * (sN + bhN));
        float hnew = (1.f - z) * n + z * hold;
        hold = (t < len) ? hnew : hold;
        if (c == 0) {
            hS[((s & 1) ^ 1) * HID + e] = hold;
            outb[(size_t)t * 256 + e] = hold;
        }
        __syncthreads();
        xvR = nxvR; xvZ = nxvZ; xvN = nxvN;
    }
}

// ---------------- K7: MLP (relu) + emissions -----------------------------
__global__ __launch_bounds__(128) void mlp_emis_k(
    const float* __restrict__ h1,    // [16384][256]
    const float* __restrict__ w1,    // [256][128]
    const float* __restrict__ b1,    // [128]
    const float* __restrict__ w2,    // [128][17]
    const float* __restrict__ b2,    // [17]
    float* __restrict__ emis)        // [16384][17]
{
    __shared__ __align__(16) float hrow[8 * 256];
    __shared__ float hid[8][HID];
    int p0 = blockIdx.x * 8;
    int tid = threadIdx.x;
    for (int e = tid; e < 8 * 256; e += 128)
        hrow[e] = h1[(size_t)p0 * 256 + e];
    __syncthreads();
    float acc[8];
    float bb = b1[tid];
    #pragma unroll
    for (int i = 0; i < 8; i++) acc[i] = bb;
    for (int k = 0; k < 256; k++) {
        float wv = w1[k * HID + tid];
        #pragma unroll
        for (int i = 0; i < 8; i++) acc[i] += hrow[i * 256 + k] * wv;
    }
    #pragma unroll
    for (int i = 0; i < 8; i++) hid[i][tid] = fmaxf(acc[i], 0.f);
    __syncthreads();
    for (int idx = tid; idx < 8 * NT; idx += 128) {
        int pos = idx / NT;
        int tg = idx - pos * NT;
        float a = b2[tg];
        for (int k = 0; k < HID; k++) a += hid[pos][k] * w2[k * NT + tg];
        emis[(size_t)(p0 + pos) * NT + tg] = a;
    }
}

// ---------------- K8: CRF score + forward algorithm ----------------------
__global__ __launch_bounds__(64) void crf_k(
    const float* __restrict__ emis,   // [64][256][17]
    const float* __restrict__ start,
    const float* __restrict__ endv,
    const float* __restrict__ trans,  // [17][17]
    const int*   __restrict__ target, // [64][256]
    const int*   __restrict__ lens,
    float* __restrict__ llh)          // [64]
{
    int b = blockIdx.x;
    int tid = threadIdx.x;
    __shared__ float tr[NT * NT];
    __shared__ float aSh[NT];
    __shared__ float scoreSh;
    for (int e = tid; e < NT * NT; e += 64) tr[e] = trans[e];
    __syncthreads();
    int len = lens[b];
    const int* tgt = target + b * SEQ;
    const float* eb = emis + (size_t)b * SEQ * NT;

    // gold score (parallel over t, reduce in-wave)
    float part = 0.f;
    for (int t = 1 + tid; t < SEQ; t += 64) {
        if (t < len) {
            int tp = tgt[t - 1], tc = tgt[t];
            part += tr[tp * NT + tc] + eb[(size_t)t * NT + tc];
        }
    }
    #pragma unroll
    for (int off = 32; off > 0; off >>= 1)
        part += __shfl_down(part, off, 64);
    if (tid == 0) {
        int t0 = tgt[0];
        scoreSh = part + start[t0] + eb[t0] + endv[tgt[len - 1]];
    }

    // forward algorithm
    float a = (tid < NT) ? (start[tid] + eb[tid]) : 0.f;
    for (int t = 1; t < SEQ; t++) {
        if (tid < NT) aSh[tid] = a;
        __syncthreads();
        if (t < len && tid < NT) {
            float m = -1e30f;
            #pragma unroll
            for (int i = 0; i < NT; i++)
                m = fmaxf(m, aSh[i] + tr[i * NT + tid]);
            float ssum = 0.f;
            #pragma unroll
            for (int i = 0; i < NT; i++)
                ssum += __expf(aSh[i] + tr[i * NT + tid] - m);
            a = m + __logf(ssum) + eb[(size_t)t * NT + tid];
        }
        __syncthreads();
    }
    float v = (tid < NT) ? (a + endv[tid]) : -1e30f;
    float m = v;
    #pragma unroll
    for (int off = 32; off > 0; off >>= 1)
        m = fmaxf(m, __shfl_down(m, off, 64));
    m = __shfl(m, 0, 64);
    float e = (tid < NT) ? __expf(v - m) : 0.f;
    #pragma unroll
    for (int off = 32; off > 0; off >>= 1)
        e += __shfl_down(e, off, 64);
    if (tid == 0) {
        float logz = m + __logf(e);
        llh[b] = scoreSh - logz;
    }
}

// ---------------- K9: final loss -----------------------------------------
__global__ __launch_bounds__(64) void finalize_k(
    const float* __restrict__ llh,
    const int*   __restrict__ lens,
    float* __restrict__ out)
{
    int tid = threadIdx.x;
    float s = llh[tid];
    float lf = (float)lens[tid];
    #pragma unroll
    for (int off = 32; off > 0; off >>= 1) {
        s += __shfl_down(s, off, 64);
        lf += __shfl_down(lf, off, 64);
    }
    if (tid == 0) out[0] = -(s / lf);
}

extern "C" void kernel_launch(void* const* d_in, const int* in_sizes, int n_in,
                              void* d_out, int out_size, void* d_ws, size_t ws_size,
                              hipStream_t stream) {
    const float* char_emb = (const float*)d_in[0];
    const float* conv_w   = (const float*)d_in[1];
    const float* conv_b   = (const float*)d_in[2];
    const float* word_emb = (const float*)d_in[3];
    const float* w_ih_l0  = (const float*)d_in[4];
    const float* w_hh_l0  = (const float*)d_in[5];
    const float* b_ih_l0  = (const float*)d_in[6];
    const float* b_hh_l0  = (const float*)d_in[7];
    const float* w_ih_l1  = (const float*)d_in[8];
    const float* w_hh_l1  = (const float*)d_in[9];
    const float* b_ih_l1  = (const float*)d_in[10];
    const float* b_hh_l1  = (const float*)d_in[11];
    const float* mlp_w1   = (const float*)d_in[12];
    const float* mlp_b1   = (const float*)d_in[13];
    const float* mlp_w2   = (const float*)d_in[14];
    const float* mlp_b2   = (const float*)d_in[15];
    const float* crf_start= (const float*)d_in[16];
    const float* crf_end  = (const float*)d_in[17];
    const float* crf_trans= (const float*)d_in[18];
    const int* bcw   = (const int*)d_in[19];
    // d_in[20] batched_char_words_len: unused by reference
    const int* bcwi  = (const int*)d_in[21];
    const int* btok  = (const int*)d_in[22];
    const int* blen  = (const int*)d_in[23];
    const int* target= (const int*)d_in[24];

    float* ws    = (float*)d_ws;
    float* xg    = ws + OFF_XG;
    float* texts = ws + OFF_TEXTS;   // aliased: h0 overwrites texts after xg0 GEMM
    float* h0    = texts;
    float* h1    = ws + OFF_H1;
    float* tok   = ws + OFF_TOK;
    float* emis  = ws + OFF_EMIS;
    float* wpad  = ws + OFF_WPAD;
    float* llh   = ws + OFF_LLH;

    hipMemsetAsync(tok, 0, CDIM * sizeof(float), stream);  // tok_enc row 0 = zeros
    pad_w_k<<<768, 64, 0, stream>>>(w_ih_l0, wpad);
    char_conv_k<<<NW / 8, 256, 0, stream>>>(char_emb, conv_w, conv_b, bcw, tok);
    build_texts_k<<<NPOS, 128, 0, stream>>>(word_emb, tok, btok, bcwi, texts);
    gemm_xg_k<<<dim3(NPOS / GBM, 768 / GBN), 256, 0, stream>>>(texts, wpad, b_ih_l0, xg, IN0P);
    gru_rec_k<<<2 * BATCH, 512, 0, stream>>>(xg, w_hh_l0, b_hh_l0, blen, h0);
    gemm_xg_k<<<dim3(NPOS / GBM, 768 / GBN), 256, 0, stream>>>(h0, w_ih_l1, b_ih_l1, xg, IN1);
    gru_rec_k<<<2 * BATCH, 512, 0, stream>>>(xg, w_hh_l1, b_hh_l1, blen, h1);
    mlp_emis_k<<<NPOS / 8, 128, 0, stream>>>(h1, mlp_w1, mlp_b1, mlp_w2, mlp_b2, emis);
    crf_k<<<BATCH, 64, 0, stream>>>(emis, crf_start, crf_end, crf_trans, target, blen, llh);
    finalize_k<<<1, 64, 0, stream>>>(llh, blen, (float*)d_out);
}

// Round 4
// 965.370 us; speedup vs baseline: 1.2425x; 1.0926x over previous
//
#include <hip/hip_runtime.h>
#include <cstddef>

// Problem dims
#define BATCH 64
#define SEQ   256
#define VOCAB 50000
#define DIM   300
#define NW    8192
#define CLEN  16
#define CDIM  30
#define CHC   30
#define HID   128
#define NT    17
#define IN0   (DIM + CHC)   // 330
#define IN0P  336           // padded to multiple of 16
#define IN1   (2 * HID)     // 256
#define NPOS  (BATCH * SEQ) // 16384

// Workspace layout (floats)
constexpr size_t SZ_XG    = 2ull * BATCH * SEQ * 384;    // 12,582,912
constexpr size_t SZ_TEXTS = (size_t)NPOS * IN0P;         // 5,505,024 (aliased as h0 after GEMM0)
constexpr size_t SZ_H1    = (size_t)NPOS * 256;          // 4,194,304
constexpr size_t SZ_TOK   = 245792;                      // (NW+1)*30 rounded
constexpr size_t SZ_EMIS  = (size_t)NPOS * NT;           // 278,528
constexpr size_t SZ_WPAD  = 768ull * IN0P;               // 258,048
constexpr size_t OFF_XG    = 0;
constexpr size_t OFF_TEXTS = OFF_XG + SZ_XG;
constexpr size_t OFF_H1    = OFF_TEXTS + SZ_TEXTS;
constexpr size_t OFF_TOK   = OFF_H1 + SZ_H1;
constexpr size_t OFF_EMIS  = OFF_TOK + SZ_TOK;
constexpr size_t OFF_WPAD  = OFF_EMIS + SZ_EMIS;
constexpr size_t OFF_LLH   = OFF_WPAD + SZ_WPAD;

__device__ __forceinline__ float sigm(float x) {
    return 1.f / (1.f + __expf(-x));
}
__device__ __forceinline__ float tanh_fast(float x) {
    x = fminf(fmaxf(x, -15.f), 15.f);
    float e = __expf(-2.f * x);
    return (1.f - e) / (1.f + e);
}
// Workgroup barrier that drains ONLY lgkmcnt (LDS), leaving global loads /
// stores (vmcnt) in flight. __syncthreads() would emit s_waitcnt vmcnt(0)
// and put the xg-prefetch HBM latency on the critical path every step.
__device__ __forceinline__ void barrier_lgkm() {
    asm volatile("s_waitcnt lgkmcnt(0)\n\ts_barrier" ::: "memory");
}

// ---------------- K1: char CNN + relu + maxpool -> tok_enc[(n+1)][30] ----
__global__ __launch_bounds__(256) void char_conv_k(
    const float* __restrict__ char_emb,  // [500][30]
    const float* __restrict__ conv_w,    // [30][30][3]
    const float* __restrict__ conv_b,    // [30]
    const int*   __restrict__ words,     // [8192][16]
    float* __restrict__ tok_enc)         // [8193][30]
{
    __shared__ __align__(16) float cs[8][CLEN][CDIM];
    __shared__ float wsm[CHC * CDIM * 3];
    __shared__ float bs[CHC];
    int n0 = blockIdx.x * 8;
    int tid = threadIdx.x;
    for (int e = tid; e < CHC * CDIM * 3; e += 256) wsm[e] = conv_w[e];
    if (tid < CHC) bs[tid] = conv_b[tid];
    for (int e = tid; e < 8 * CLEN * CDIM; e += 256) {
        int wi = e / (CLEN * CDIM);
        int rem = e - wi * (CLEN * CDIM);
        int l = rem / CDIM;
        int i = rem - l * CDIM;
        int ci = words[(n0 + wi) * CLEN + l];
        cs[wi][l][i] = char_emb[ci * CDIM + i];
    }
    __syncthreads();
    int wi = tid >> 5;
    int o = tid & 31;
    if (o < CHC) {
        float best = -1e30f;
        for (int l = 0; l < CLEN; l++) {
            float s = 0.f;
            #pragma unroll
            for (int k = 0; k < 3; k++) {
                int ll = l + k - 1;
                if (ll >= 0 && ll < CLEN) {
                    #pragma unroll
                    for (int i = 0; i < CDIM; i++)
                        s += cs[wi][ll][i] * wsm[(o * CDIM + i) * 3 + k];
                }
            }
            best = fmaxf(best, s);
        }
        tok_enc[(size_t)(n0 + wi + 1) * CDIM + o] = fmaxf(best + bs[o], 0.f);
    }
}

// ---------------- K2: texts = concat(word_emb[tok], tok_enc[widx]), pad to 336
__global__ __launch_bounds__(128) void build_texts_k(
    const float* __restrict__ word_emb,
    const float* __restrict__ tok_enc,
    const int*   __restrict__ tokens,
    const int*   __restrict__ widx,
    float* __restrict__ texts)
{
    int p = blockIdx.x;
    int tok = tokens[p];
    int ci = widx[p];
    float* o = texts + (size_t)p * IN0P;
    const float* wr = word_emb + (size_t)tok * DIM;
    const float* tr = tok_enc + (size_t)ci * CDIM;
    for (int c = threadIdx.x; c < IN0P; c += 128)
        o[c] = (c < DIM) ? wr[c] : (c < IN0 ? tr[c - DIM] : 0.f);
}

// ---------------- K2b: pad w_ih_l0 (768x330) -> (768x336) ---------------
__global__ __launch_bounds__(64) void pad_w_k(
    const float* __restrict__ w, float* __restrict__ wp)
{
    int r = blockIdx.x;
    for (int c = threadIdx.x; c < IN0P; c += 64)
        wp[(size_t)r * IN0P + c] = (c < IN0) ? w[(size_t)r * IN0 + c] : 0.f;
}

// ---------------- K3/K5: xg = A @ W_ih^T + b_ih, stored [d][b][t][g] -----
// A: [16384][K] row-major (K multiple of 16), W: [768][K] row-major
#define GBM 128
#define GBN 128
#define GBK 16
__global__ __launch_bounds__(256) void gemm_xg_k(
    const float* __restrict__ A,
    const float* __restrict__ W,
    const float* __restrict__ bias,
    float* __restrict__ out,
    int K)
{
    __shared__ __align__(16) float As[GBK][GBM];
    __shared__ __align__(16) float Ws[GBK][GBN];
    int tid = threadIdx.x;
    int m0 = blockIdx.x * GBM;
    int n0 = blockIdx.y * GBN;
    int lrow = tid >> 1;
    int lk = (tid & 1) * 8;
    int ty = tid >> 4;   // 0..15 (m)
    int tx = tid & 15;   // 0..15 (n)

    float acc[8][8];
    #pragma unroll
    for (int i = 0; i < 8; i++)
        #pragma unroll
        for (int j = 0; j < 8; j++) acc[i][j] = 0.f;

    for (int k0 = 0; k0 < K; k0 += GBK) {
        const float4* ap = (const float4*)(A + (size_t)(m0 + lrow) * K + k0 + lk);
        const float4* wp = (const float4*)(W + (size_t)(n0 + lrow) * K + k0 + lk);
        float4 va0 = ap[0], va1 = ap[1];
        float4 vw0 = wp[0], vw1 = wp[1];
        As[lk + 0][lrow] = va0.x; As[lk + 1][lrow] = va0.y;
        As[lk + 2][lrow] = va0.z; As[lk + 3][lrow] = va0.w;
        As[lk + 4][lrow] = va1.x; As[lk + 5][lrow] = va1.y;
        As[lk + 6][lrow] = va1.z; As[lk + 7][lrow] = va1.w;
        Ws[lk + 0][lrow] = vw0.x; Ws[lk + 1][lrow] = vw0.y;
        Ws[lk + 2][lrow] = vw0.z; Ws[lk + 3][lrow] = vw0.w;
        Ws[lk + 4][lrow] = vw1.x; Ws[lk + 5][lrow] = vw1.y;
        Ws[lk + 6][lrow] = vw1.z; Ws[lk + 7][lrow] = vw1.w;
        __syncthreads();
        #pragma unroll
        for (int k = 0; k < GBK; k++) {
            float4 a0 = *(const float4*)&As[k][ty * 8];
            float4 a1 = *(const float4*)&As[k][ty * 8 + 4];
            float4 b0 = *(const float4*)&Ws[k][tx * 8];
            float4 b1 = *(const float4*)&Ws[k][tx * 8 + 4];
            float av[8] = {a0.x, a0.y, a0.z, a0.w, a1.x, a1.y, a1.z, a1.w};
            float bv[8] = {b0.x, b0.y, b0.z, b0.w, b1.x, b1.y, b1.z, b1.w};
            #pragma unroll
            for (int i = 0; i < 8; i++)
                #pragma unroll
                for (int j = 0; j < 8; j++)
                    acc[i][j] += av[i] * bv[j];
        }
        __syncthreads();
    }
    // store to xg layout: ((d*64+b)*256+t)*384 + g
    int nb = n0 + tx * 8;
    int d = nb / 384;
    int g0 = nb - d * 384;
    float bvv[8];
    #pragma unroll
    for (int j = 0; j < 8; j++) bvv[j] = bias[nb + j];
    int mbase = m0 + ty * 8;
    #pragma unroll
    for (int i = 0; i < 8; i++) {
        int m = mbase + i;
        int b = m >> 8;
        int t = m & 255;
        float* op = out + (((size_t)(d * BATCH + b) * SEQ + t) * 384 + g0);
        #pragma unroll
        for (int j = 0; j < 8; j++) op[j] = acc[i][j] + bvv[j];
    }
}

// ---------------- K4/K6: GRU recurrence, one wg per (dir, batch) ---------
// R1 structure (384 thr, 1 weight row/thread, broadcast LDS h reads, 0 bank
// conflicts) + lgkm-only barriers so the xg prefetch and out stores stay in
// flight across steps. Weights live in AGPRs (unified file), read directly
// by v_fma. hold carried in n-thread registers. b_ih folded into xg.
__global__ __launch_bounds__(384, 1) void gru_rec_k(
    const float* __restrict__ xg,    // [2][64][256][384]
    const float* __restrict__ w_hh,  // [2][384][128]
    const float* __restrict__ b_hh,  // [2][384]
    const int*   __restrict__ lens,  // [64]
    float* __restrict__ out)         // [64][256][256], channel = d*128+j
{
    int d = blockIdx.x & 1;
    int b = blockIdx.x >> 1;
    int g = threadIdx.x;   // 0..383 = gate row
    __shared__ __align__(16) float h[HID];
    __shared__ float srz[256];

    float4 w[32];
    {
        const float4* wr = (const float4*)(w_hh + ((size_t)d * 384 + g) * HID);
        #pragma unroll
        for (int q = 0; q < 32; q++) w[q] = wr[q];
    }
    float bh = b_hh[d * 384 + g];
    int len = lens[b];

    if (g < HID) h[g] = 0.f;
    float hold = 0.f;
    __syncthreads();

    const float* xgb = xg + ((size_t)(d * BATCH + b)) * SEQ * 384;
    float* outb = out + (size_t)b * SEQ * 256 + d * HID;

    int t0 = d ? (SEQ - 1) : 0;
    float pxv = xgb[(size_t)t0 * 384 + g];

    for (int s = 0; s < SEQ; s++) {
        int t = d ? (SEQ - 1 - s) : s;
        float xv = pxv;
        // prefetch next step's xg; stays in flight across the lgkm barriers
        int sn = (s + 1 < SEQ) ? (s + 1) : s;
        int tn = d ? (SEQ - 1 - sn) : sn;
        pxv = xgb[(size_t)tn * 384 + g];

        const float4* h4 = (const float4*)h;
        float sx = 0.f, sy = 0.f, sz = 0.f, sw = 0.f;
        #pragma unroll
        for (int q = 0; q < 32; q++) {
            float4 hv = h4[q];
            sx += w[q].x * hv.x;
            sy += w[q].y * hv.y;
            sz += w[q].z * hv.z;
            sw += w[q].w * hv.w;
        }
        float acc = bh + ((sx + sy) + (sz + sw));
        if (g < 256) srz[g] = sigm(xv + acc);
        barrier_lgkm();
        if (g >= 256) {
            int j = g - 256;
            float r = srz[j];
            float z = srz[HID + j];
            float n = tanh_fast(xv + r * acc);
            float hnew = (1.f - z) * n + z * hold;
            hold = (t < len) ? hnew : hold;
            h[j] = hold;
            outb[(size_t)t * 256 + j] = hold;
        }
        barrier_lgkm();
    }
}

// ---------------- K7: MLP (relu) + emissions -----------------------------
__global__ __launch_bounds__(128) void mlp_emis_k(
    const float* __restrict__ h1,    // [16384][256]
    const float* __restrict__ w1,    // [256][128]
    const float* __restrict__ b1,    // [128]
    const float* __restrict__ w2,    // [128][17]
    const float* __restrict__ b2,    // [17]
    float* __restrict__ emis)        // [16384][17]
{
    __shared__ __align__(16) float hrow[8 * 256];
    __shared__ float hid[8][HID];
    int p0 = blockIdx.x * 8;
    int tid = threadIdx.x;
    for (int e = tid; e < 8 * 256; e += 128)
        hrow[e] = h1[(size_t)p0 * 256 + e];
    __syncthreads();
    float acc[8];
    float bb = b1[tid];
    #pragma unroll
    for (int i = 0; i < 8; i++) acc[i] = bb;
    for (int k = 0; k < 256; k++) {
        float wv = w1[k * HID + tid];
        #pragma unroll
        for (int i = 0; i < 8; i++) acc[i] += hrow[i * 256 + k] * wv;
    }
    #pragma unroll
    for (int i = 0; i < 8; i++) hid[i][tid] = fmaxf(acc[i], 0.f);
    __syncthreads();
    for (int idx = tid; idx < 8 * NT; idx += 128) {
        int pos = idx / NT;
        int tg = idx - pos * NT;
        float a = b2[tg];
        for (int k = 0; k < HID; k++) a += hid[pos][k] * w2[k * NT + tg];
        emis[(size_t)(p0 + pos) * NT + tg] = a;
    }
}

// ---------------- K8: CRF score + forward algorithm ----------------------
__global__ __launch_bounds__(64) void crf_k(
    const float* __restrict__ emis,   // [64][256][17]
    const float* __restrict__ start,
    const float* __restrict__ endv,
    const float* __restrict__ trans,  // [17][17]
    const int*   __restrict__ target, // [64][256]
    const int*   __restrict__ lens,
    float* __restrict__ llh)          // [64]
{
    int b = blockIdx.x;
    int tid = threadIdx.x;
    __shared__ float tr[NT * NT];
    __shared__ float aSh[NT];
    __shared__ float scoreSh;
    for (int e = tid; e < NT * NT; e += 64) tr[e] = trans[e];
    __syncthreads();
    int len = lens[b];
    const int* tgt = target + b * SEQ;
    const float* eb = emis + (size_t)b * SEQ * NT;

    // gold score (parallel over t, reduce in-wave)
    float part = 0.f;
    for (int t = 1 + tid; t < SEQ; t += 64) {
        if (t < len) {
            int tp = tgt[t - 1], tc = tgt[t];
            part += tr[tp * NT + tc] + eb[(size_t)t * NT + tc];
        }
    }
    #pragma unroll
    for (int off = 32; off > 0; off >>= 1)
        part += __shfl_down(part, off, 64);
    if (tid == 0) {
        int t0 = tgt[0];
        scoreSh = part + start[t0] + eb[t0] + endv[tgt[len - 1]];
    }

    // forward algorithm
    float a = (tid < NT) ? (start[tid] + eb[tid]) : 0.f;
    for (int t = 1; t < SEQ; t++) {
        if (tid < NT) aSh[tid] = a;
        __syncthreads();
        if (t < len && tid < NT) {
            float m = -1e30f;
            #pragma unroll
            for (int i = 0; i < NT; i++)
                m = fmaxf(m, aSh[i] + tr[i * NT + tid]);
            float ssum = 0.f;
            #pragma unroll
            for (int i = 0; i < NT; i++)
                ssum += __expf(aSh[i] + tr[i * NT + tid] - m);
            a = m + __logf(ssum) + eb[(size_t)t * NT + tid];
        }
        __syncthreads();
    }
    float v = (tid < NT) ? (a + endv[tid]) : -1e30f;
    float m = v;
    #pragma unroll
    for (int off = 32; off > 0; off >>= 1)
        m = fmaxf(m, __shfl_down(m, off, 64));
    m = __shfl(m, 0, 64);
    float e = (tid < NT) ? __expf(v - m) : 0.f;
    #pragma unroll
    for (int off = 32; off > 0; off >>= 1)
        e += __shfl_down(e, off, 64);
    if (tid == 0) {
        float logz = m + __logf(e);
        llh[b] = scoreSh - logz;
    }
}

// ---------------- K9: final loss -----------------------------------------
__global__ __launch_bounds__(64) void finalize_k(
    const float* __restrict__ llh,
    const int*   __restrict__ lens,
    float* __restrict__ out)
{
    int tid = threadIdx.x;
    float s = llh[tid];
    float lf = (float)lens[tid];
    #pragma unroll
    for (int off = 32; off > 0; off >>= 1) {
        s += __shfl_down(s, off, 64);
        lf += __shfl_down(lf, off, 64);
    }
    if (tid == 0) out[0] = -(s / lf);
}

extern "C" void kernel_launch(void* const* d_in, const int* in_sizes, int n_in,
                              void* d_out, int out_size, void* d_ws, size_t ws_size,
                              hipStream_t stream) {
    const float* char_emb = (const float*)d_in[0];
    const float* conv_w   = (const float*)d_in[1];
    const float* conv_b   = (const float*)d_in[2];
    const float* word_emb = (const float*)d_in[3];
    const float* w_ih_l0  = (const float*)d_in[4];
    const float* w_hh_l0  = (const float*)d_in[5];
    const float* b_ih_l0  = (const float*)d_in[6];
    const float* b_hh_l0  = (const float*)d_in[7];
    const float* w_ih_l1  = (const float*)d_in[8];
    const float* w_hh_l1  = (const float*)d_in[9];
    const float* b_ih_l1  = (const float*)d_in[10];
    const float* b_hh_l1  = (const float*)d_in[11];
    const float* mlp_w1   = (const float*)d_in[12];
    const float* mlp_b1   = (const float*)d_in[13];
    const float* mlp_w2   = (const float*)d_in[14];
    const float* mlp_b2   = (const float*)d_in[15];
    const float* crf_start= (const float*)d_in[16];
    const float* crf_end  = (const float*)d_in[17];
    const float* crf_trans= (const float*)d_in[18];
    const int* bcw   = (const int*)d_in[19];
    // d_in[20] batched_char_words_len: unused by reference
    const int* bcwi  = (const int*)d_in[21];
    const int* btok  = (const int*)d_in[22];
    const int* blen  = (const int*)d_in[23];
    const int* target= (const int*)d_in[24];

    float* ws    = (float*)d_ws;
    float* xg    = ws + OFF_XG;
    float* texts = ws + OFF_TEXTS;   // aliased: h0 overwrites texts after xg0 GEMM
    float* h0    = texts;
    float* h1    = ws + OFF_H1;
    float* tok   = ws + OFF_TOK;
    float* emis  = ws + OFF_EMIS;
    float* wpad  = ws + OFF_WPAD;
    float* llh   = ws + OFF_LLH;

    hipMemsetAsync(tok, 0, CDIM * sizeof(float), stream);  // tok_enc row 0 = zeros
    pad_w_k<<<768, 64, 0, stream>>>(w_ih_l0, wpad);
    char_conv_k<<<NW / 8, 256, 0, stream>>>(char_emb, conv_w, conv_b, bcw, tok);
    build_texts_k<<<NPOS, 128, 0, stream>>>(word_emb, tok, btok, bcwi, texts);
    gemm_xg_k<<<dim3(NPOS / GBM, 768 / GBN), 256, 0, stream>>>(texts, wpad, b_ih_l0, xg, IN0P);
    gru_rec_k<<<2 * BATCH, 384, 0, stream>>>(xg, w_hh_l0, b_hh_l0, blen, h0);
    gemm_xg_k<<<dim3(NPOS / GBM, 768 / GBN), 256, 0, stream>>>(h0, w_ih_l1, b_ih_l1, xg, IN1);
    gru_rec_k<<<2 * BATCH, 384, 0, stream>>>(xg, w_hh_l1, b_hh_l1, blen, h1);
    mlp_emis_k<<<NPOS / 8, 128, 0, stream>>>(h1, mlp_w1, mlp_b1, mlp_w2, mlp_b2, emis);
    crf_k<<<BATCH, 64, 0, stream>>>(emis, crf_start, crf_end, crf_trans, target, blen, llh);
    finalize_k<<<1, 64, 0, stream>>>(llh, blen, (float*)d_out);
}

// Round 5
// 879.458 us; speedup vs baseline: 1.3638x; 1.0977x over previous
//
#include <hip/hip_runtime.h>
#include <cstddef>

// Problem dims
#define BATCH 64
#define SEQ   256
#define VOCAB 50000
#define DIM   300
#define NW    8192
#define CLEN  16
#define CDIM  30
#define CHC   30
#define HID   128
#define NT    17
#define IN0   (DIM + CHC)   // 330
#define IN0P  336           // padded to multiple of 16
#define IN1   (2 * HID)     // 256
#define NPOS  (BATCH * SEQ) // 16384

// Workspace layout (floats)
constexpr size_t SZ_XG    = 2ull * BATCH * SEQ * 384;    // 12,582,912
constexpr size_t SZ_TEXTS = (size_t)NPOS * IN0P;         // 5,505,024 (aliased as h0 after GEMM0)
constexpr size_t SZ_H1    = (size_t)NPOS * 256;          // 4,194,304
constexpr size_t SZ_TOK   = 245792;                      // (NW+1)*30 rounded
constexpr size_t SZ_EMIS  = (size_t)NPOS * NT;           // 278,528
constexpr size_t SZ_WPAD  = 768ull * IN0P;               // 258,048
constexpr size_t OFF_XG    = 0;
constexpr size_t OFF_TEXTS = OFF_XG + SZ_XG;
constexpr size_t OFF_H1    = OFF_TEXTS + SZ_TEXTS;
constexpr size_t OFF_TOK   = OFF_H1 + SZ_H1;
constexpr size_t OFF_EMIS  = OFF_TOK + SZ_TOK;
constexpr size_t OFF_WPAD  = OFF_EMIS + SZ_EMIS;
constexpr size_t OFF_LLH   = OFF_WPAD + SZ_WPAD;

__device__ __forceinline__ float sigm(float x) {
    return 1.f / (1.f + __expf(-x));
}
__device__ __forceinline__ float tanh_fast(float x) {
    x = fminf(fmaxf(x, -15.f), 15.f);
    float e = __expf(-2.f * x);
    return (1.f - e) / (1.f + e);
}
// Sum across the 4 lanes of a quad using DPP quad_perm (VALU-only; no LDS
// pipe, unlike __shfl which compiles to ds_bpermute).
__device__ __forceinline__ float quad_sum(float x) {
    int y = __builtin_amdgcn_update_dpp(0, __float_as_int(x), 0xB1, 0xF, 0xF, false); // [1,0,3,2]
    x += __int_as_float(y);
    y = __builtin_amdgcn_update_dpp(0, __float_as_int(x), 0x4E, 0xF, 0xF, false);     // [2,3,0,1]
    x += __int_as_float(y);
    return x;
}

// ---------------- K1: char CNN + relu + maxpool -> tok_enc[(n+1)][30] ----
__global__ __launch_bounds__(256) void char_conv_k(
    const float* __restrict__ char_emb,  // [500][30]
    const float* __restrict__ conv_w,    // [30][30][3]
    const float* __restrict__ conv_b,    // [30]
    const int*   __restrict__ words,     // [8192][16]
    float* __restrict__ tok_enc)         // [8193][30]
{
    __shared__ __align__(16) float cs[8][CLEN][CDIM];
    __shared__ float wsm[CHC * CDIM * 3];
    __shared__ float bs[CHC];
    int n0 = blockIdx.x * 8;
    int tid = threadIdx.x;
    for (int e = tid; e < CHC * CDIM * 3; e += 256) wsm[e] = conv_w[e];
    if (tid < CHC) bs[tid] = conv_b[tid];
    for (int e = tid; e < 8 * CLEN * CDIM; e += 256) {
        int wi = e / (CLEN * CDIM);
        int rem = e - wi * (CLEN * CDIM);
        int l = rem / CDIM;
        int i = rem - l * CDIM;
        int ci = words[(n0 + wi) * CLEN + l];
        cs[wi][l][i] = char_emb[ci * CDIM + i];
    }
    __syncthreads();
    int wi = tid >> 5;
    int o = tid & 31;
    if (o < CHC) {
        float best = -1e30f;
        for (int l = 0; l < CLEN; l++) {
            float s = 0.f;
            #pragma unroll
            for (int k = 0; k < 3; k++) {
                int ll = l + k - 1;
                if (ll >= 0 && ll < CLEN) {
                    #pragma unroll
                    for (int i = 0; i < CDIM; i++)
                        s += cs[wi][ll][i] * wsm[(o * CDIM + i) * 3 + k];
                }
            }
            best = fmaxf(best, s);
        }
        tok_enc[(size_t)(n0 + wi + 1) * CDIM + o] = fmaxf(best + bs[o], 0.f);
    }
}

// ---------------- K2: texts = concat(word_emb[tok], tok_enc[widx]), pad to 336
__global__ __launch_bounds__(128) void build_texts_k(
    const float* __restrict__ word_emb,
    const float* __restrict__ tok_enc,
    const int*   __restrict__ tokens,
    const int*   __restrict__ widx,
    float* __restrict__ texts)
{
    int p = blockIdx.x;
    int tok = tokens[p];
    int ci = widx[p];
    float* o = texts + (size_t)p * IN0P;
    const float* wr = word_emb + (size_t)tok * DIM;
    const float* tr = tok_enc + (size_t)ci * CDIM;
    for (int c = threadIdx.x; c < IN0P; c += 128)
        o[c] = (c < DIM) ? wr[c] : (c < IN0 ? tr[c - DIM] : 0.f);
}

// ---------------- K2b: pad w_ih_l0 (768x330) -> (768x336) ---------------
__global__ __launch_bounds__(64) void pad_w_k(
    const float* __restrict__ w, float* __restrict__ wp)
{
    int r = blockIdx.x;
    for (int c = threadIdx.x; c < IN0P; c += 64)
        wp[(size_t)r * IN0P + c] = (c < IN0) ? w[(size_t)r * IN0 + c] : 0.f;
}

// ---------------- K3/K5: xg = A @ W_ih^T + b_ih, stored [d][b][t][g] -----
// A: [16384][K] row-major (K multiple of 16), W: [768][K] row-major
#define GBM 128
#define GBN 128
#define GBK 16
__global__ __launch_bounds__(256) void gemm_xg_k(
    const float* __restrict__ A,
    const float* __restrict__ W,
    const float* __restrict__ bias,
    float* __restrict__ out,
    int K)
{
    __shared__ __align__(16) float As[GBK][GBM];
    __shared__ __align__(16) float Ws[GBK][GBN];
    int tid = threadIdx.x;
    int m0 = blockIdx.x * GBM;
    int n0 = blockIdx.y * GBN;
    int lrow = tid >> 1;
    int lk = (tid & 1) * 8;
    int ty = tid >> 4;   // 0..15 (m)
    int tx = tid & 15;   // 0..15 (n)

    float acc[8][8];
    #pragma unroll
    for (int i = 0; i < 8; i++)
        #pragma unroll
        for (int j = 0; j < 8; j++) acc[i][j] = 0.f;

    for (int k0 = 0; k0 < K; k0 += GBK) {
        const float4* ap = (const float4*)(A + (size_t)(m0 + lrow) * K + k0 + lk);
        const float4* wp = (const float4*)(W + (size_t)(n0 + lrow) * K + k0 + lk);
        float4 va0 = ap[0], va1 = ap[1];
        float4 vw0 = wp[0], vw1 = wp[1];
        As[lk + 0][lrow] = va0.x; As[lk + 1][lrow] = va0.y;
        As[lk + 2][lrow] = va0.z; As[lk + 3][lrow] = va0.w;
        As[lk + 4][lrow] = va1.x; As[lk + 5][lrow] = va1.y;
        As[lk + 6][lrow] = va1.z; As[lk + 7][lrow] = va1.w;
        Ws[lk + 0][lrow] = vw0.x; Ws[lk + 1][lrow] = vw0.y;
        Ws[lk + 2][lrow] = vw0.z; Ws[lk + 3][lrow] = vw0.w;
        Ws[lk + 4][lrow] = vw1.x; Ws[lk + 5][lrow] = vw1.y;
        Ws[lk + 6][lrow] = vw1.z; Ws[lk + 7][lrow] = vw1.w;
        __syncthreads();
        #pragma unroll
        for (int k = 0; k < GBK; k++) {
            float4 a0 = *(const float4*)&As[k][ty * 8];
            float4 a1 = *(const float4*)&As[k][ty * 8 + 4];
            float4 b0 = *(const float4*)&Ws[k][tx * 8];
            float4 b1 = *(const float4*)&Ws[k][tx * 8 + 4];
            float av[8] = {a0.x, a0.y, a0.z, a0.w, a1.x, a1.y, a1.z, a1.w};
            float bv[8] = {b0.x, b0.y, b0.z, b0.w, b1.x, b1.y, b1.z, b1.w};
            #pragma unroll
            for (int i = 0; i < 8; i++)
                #pragma unroll
                for (int j = 0; j < 8; j++)
                    acc[i][j] += av[i] * bv[j];
        }
        __syncthreads();
    }
    // store to xg layout: ((d*64+b)*256+t)*384 + g
    int nb = n0 + tx * 8;
    int d = nb / 384;
    int g0 = nb - d * 384;
    float bvv[8];
    #pragma unroll
    for (int j = 0; j < 8; j++) bvv[j] = bias[nb + j];
    int mbase = m0 + ty * 8;
    #pragma unroll
    for (int i = 0; i < 8; i++) {
        int m = mbase + i;
        int b = m >> 8;
        int t = m & 255;
        float* op = out + (((size_t)(d * BATCH + b) * SEQ + t) * 384 + g0);
        #pragma unroll
        for (int j = 0; j < 8; j++) op[j] = acc[i][j] + bvv[j];
    }
}

// ---------------- K4/K6: GRU recurrence, one wg per (dir, batch) ---------
// 512 threads: thread (e = i>>2, c = i&3) owns gate rows {e, 128+e, 256+e}
// restricted to k-chunk [32c, 32c+32). LDS-pipe ops cut 3x vs the 384-thr
// version: 8 ds_read_b128 per thread (rotation-swizzled so the 4 per-quad
// addresses hit disjoint bank groups -> conflict-free), quad reduction via
// DPP (VALU), single barrier per step via double-buffered h. The out store
// is deferred one step so its vmcnt drain at the barrier is hidden.
__global__ __launch_bounds__(512, 2) void gru_rec_k(
    const float* __restrict__ xg,    // [2][64][256][384]
    const float* __restrict__ w_hh,  // [2][384][128]
    const float* __restrict__ b_hh,  // [2][384]
    const int*   __restrict__ lens,  // [64]
    float* __restrict__ out)         // [64][256][256], channel = d*128+j
{
    int d = blockIdx.x & 1;
    int b = blockIdx.x >> 1;
    int i = threadIdx.x;   // 0..511
    int e = i >> 2;        // 0..127 hidden index
    int c = i & 3;         // 0..3 k-chunk
    __shared__ __align__(16) float hS[2][HID];

    int rR = e, rZ = HID + e, rN = 2 * HID + e;
    const float* wbR = w_hh + ((size_t)d * 384 + rR) * HID + 32 * c;
    const float* wbZ = w_hh + ((size_t)d * 384 + rZ) * HID + 32 * c;
    const float* wbN = w_hh + ((size_t)d * 384 + rN) * HID + 32 * c;
    // Preload weights in the rotated order matching the swizzled h reads:
    // iteration q consumes k-float4 m = (q + c) & 7 of this thread's chunk.
    float4 wR[8], wZ[8], wN[8];
    #pragma unroll
    for (int q = 0; q < 8; q++) {
        int m = (q + c) & 7;
        wR[q] = *(const float4*)(wbR + 4 * m);
        wZ[q] = *(const float4*)(wbZ + 4 * m);
        wN[q] = *(const float4*)(wbN + 4 * m);
    }
    float bhR = b_hh[d * 384 + rR];
    float bhZ = b_hh[d * 384 + rZ];
    float bhN = b_hh[d * 384 + rN];
    int len = lens[b];

    if (i < HID) { hS[0][i] = 0.f; }
    float hold = 0.f;
    __syncthreads();

    const float* xgb = xg + ((size_t)(d * BATCH + b)) * SEQ * 384;
    float* outb = out + (size_t)b * SEQ * 256 + d * HID;

    int t0 = d ? (SEQ - 1) : 0;
    float xvR = xgb[(size_t)t0 * 384 + rR];
    float xvZ = xgb[(size_t)t0 * 384 + rZ];
    float xvN = xgb[(size_t)t0 * 384 + rN];
    int tPrev = 0;

    for (int s = 0; s < SEQ; s++) {
        int t = d ? (SEQ - 1 - s) : s;
        // deferred out-store of the previous step's h (drains at this step's
        // barrier, fully hidden behind the dot-product work)
        if (s && c == 0) outb[(size_t)tPrev * 256 + e] = hold;
        // prefetch next step's xg
        int sn = (s + 1 < SEQ) ? (s + 1) : s;
        int tn = d ? (SEQ - 1 - sn) : sn;
        float nxvR = xgb[(size_t)tn * 384 + rR];
        float nxvZ = xgb[(size_t)tn * 384 + rZ];
        float nxvN = xgb[(size_t)tn * 384 + rN];

        const float4* hb = (const float4*)hS[s & 1] + 8 * c;
        float sR = 0.f, sZ = 0.f, sN = 0.f;
        #pragma unroll
        for (int q = 0; q < 8; q++) {
            int m = (q + c) & 7;
            float4 hv = hb[m];
            sR += wR[q].x * hv.x + wR[q].y * hv.y + wR[q].z * hv.z + wR[q].w * hv.w;
            sZ += wZ[q].x * hv.x + wZ[q].y * hv.y + wZ[q].z * hv.z + wZ[q].w * hv.w;
            sN += wN[q].x * hv.x + wN[q].y * hv.y + wN[q].z * hv.z + wN[q].w * hv.w;
        }
        sR = quad_sum(sR);
        sZ = quad_sum(sZ);
        sN = quad_sum(sN);

        float r = sigm(xvR + sR + bhR);
        float z = sigm(xvZ + sZ + bhZ);
        float n = tanh_fast(xvN + r * (sN + bhN));
        float hnew = (1.f - z) * n + z * hold;
        hold = (t < len) ? hnew : hold;
        if (c == 0) hS[(s & 1) ^ 1][e] = hold;
        tPrev = t;
        xvR = nxvR; xvZ = nxvZ; xvN = nxvN;
        __syncthreads();
    }
    if (c == 0) outb[(size_t)tPrev * 256 + e] = hold;
}

// ---------------- K7: MLP (relu) + emissions -----------------------------
__global__ __launch_bounds__(128) void mlp_emis_k(
    const float* __restrict__ h1,    // [16384][256]
    const float* __restrict__ w1,    // [256][128]
    const float* __restrict__ b1,    // [128]
    const float* __restrict__ w2,    // [128][17]
    const float* __restrict__ b2,    // [17]
    float* __restrict__ emis)        // [16384][17]
{
    __shared__ __align__(16) float hrow[8 * 256];
    __shared__ float hid[8][HID];
    int p0 = blockIdx.x * 8;
    int tid = threadIdx.x;
    for (int e = tid; e < 8 * 256; e += 128)
        hrow[e] = h1[(size_t)p0 * 256 + e];
    __syncthreads();
    float acc[8];
    float bb = b1[tid];
    #pragma unroll
    for (int i = 0; i < 8; i++) acc[i] = bb;
    for (int k = 0; k < 256; k++) {
        float wv = w1[k * HID + tid];
        #pragma unroll
        for (int i = 0; i < 8; i++) acc[i] += hrow[i * 256 + k] * wv;
    }
    #pragma unroll
    for (int i = 0; i < 8; i++) hid[i][tid] = fmaxf(acc[i], 0.f);
    __syncthreads();
    for (int idx = tid; idx < 8 * NT; idx += 128) {
        int pos = idx / NT;
        int tg = idx - pos * NT;
        float a = b2[tg];
        for (int k = 0; k < HID; k++) a += hid[pos][k] * w2[k * NT + tg];
        emis[(size_t)(p0 + pos) * NT + tg] = a;
    }
}

// ---------------- K8: CRF score + forward algorithm ----------------------
__global__ __launch_bounds__(64) void crf_k(
    const float* __restrict__ emis,   // [64][256][17]
    const float* __restrict__ start,
    const float* __restrict__ endv,
    const float* __restrict__ trans,  // [17][17]
    const int*   __restrict__ target, // [64][256]
    const int*   __restrict__ lens,
    float* __restrict__ llh)          // [64]
{
    int b = blockIdx.x;
    int tid = threadIdx.x;
    __shared__ float tr[NT * NT];
    __shared__ float aSh[NT];
    __shared__ float scoreSh;
    for (int e = tid; e < NT * NT; e += 64) tr[e] = trans[e];
    __syncthreads();
    int len = lens[b];
    const int* tgt = target + b * SEQ;
    const float* eb = emis + (size_t)b * SEQ * NT;

    // gold score (parallel over t, reduce in-wave)
    float part = 0.f;
    for (int t = 1 + tid; t < SEQ; t += 64) {
        if (t < len) {
            int tp = tgt[t - 1], tc = tgt[t];
            part += tr[tp * NT + tc] + eb[(size_t)t * NT + tc];
        }
    }
    #pragma unroll
    for (int off = 32; off > 0; off >>= 1)
        part += __shfl_down(part, off, 64);
    if (tid == 0) {
        int t0 = tgt[0];
        scoreSh = part + start[t0] + eb[t0] + endv[tgt[len - 1]];
    }

    // forward algorithm
    float a = (tid < NT) ? (start[tid] + eb[tid]) : 0.f;
    for (int t = 1; t < SEQ; t++) {
        if (tid < NT) aSh[tid] = a;
        __syncthreads();
        if (t < len && tid < NT) {
            float m = -1e30f;
            #pragma unroll
            for (int i = 0; i < NT; i++)
                m = fmaxf(m, aSh[i] + tr[i * NT + tid]);
            float ssum = 0.f;
            #pragma unroll
            for (int i = 0; i < NT; i++)
                ssum += __expf(aSh[i] + tr[i * NT + tid] - m);
            a = m + __logf(ssum) + eb[(size_t)t * NT + tid];
        }
        __syncthreads();
    }
    float v = (tid < NT) ? (a + endv[tid]) : -1e30f;
    float m = v;
    #pragma unroll
    for (int off = 32; off > 0; off >>= 1)
        m = fmaxf(m, __shfl_down(m, off, 64));
    m = __shfl(m, 0, 64);
    float e = (tid < NT) ? __expf(v - m) : 0.f;
    #pragma unroll
    for (int off = 32; off > 0; off >>= 1)
        e += __shfl_down(e, off, 64);
    if (tid == 0) {
        float logz = m + __logf(e);
        llh[b] = scoreSh - logz;
    }
}

// ---------------- K9: final loss -----------------------------------------
__global__ __launch_bounds__(64) void finalize_k(
    const float* __restrict__ llh,
    const int*   __restrict__ lens,
    float* __restrict__ out)
{
    int tid = threadIdx.x;
    float s = llh[tid];
    float lf = (float)lens[tid];
    #pragma unroll
    for (int off = 32; off > 0; off >>= 1) {
        s += __shfl_down(s, off, 64);
        lf += __shfl_down(lf, off, 64);
    }
    if (tid == 0) out[0] = -(s / lf);
}

extern "C" void kernel_launch(void* const* d_in, const int* in_sizes, int n_in,
                              void* d_out, int out_size, void* d_ws, size_t ws_size,
                              hipStream_t stream) {
    const float* char_emb = (const float*)d_in[0];
    const float* conv_w   = (const float*)d_in[1];
    const float* conv_b   = (const float*)d_in[2];
    const float* word_emb = (const float*)d_in[3];
    const float* w_ih_l0  = (const float*)d_in[4];
    const float* w_hh_l0  = (const float*)d_in[5];
    const float* b_ih_l0  = (const float*)d_in[6];
    const float* b_hh_l0  = (const float*)d_in[7];
    const float* w_ih_l1  = (const float*)d_in[8];
    const float* w_hh_l1  = (const float*)d_in[9];
    const float* b_ih_l1  = (const float*)d_in[10];
    const float* b_hh_l1  = (const float*)d_in[11];
    const float* mlp_w1   = (const float*)d_in[12];
    const float* mlp_b1   = (const float*)d_in[13];
    const float* mlp_w2   = (const float*)d_in[14];
    const float* mlp_b2   = (const float*)d_in[15];
    const float* crf_start= (const float*)d_in[16];
    const float* crf_end  = (const float*)d_in[17];
    const float* crf_trans= (const float*)d_in[18];
    const int* bcw   = (const int*)d_in[19];
    // d_in[20] batched_char_words_len: unused by reference
    const int* bcwi  = (const int*)d_in[21];
    const int* btok  = (const int*)d_in[22];
    const int* blen  = (const int*)d_in[23];
    const int* target= (const int*)d_in[24];

    float* ws    = (float*)d_ws;
    float* xg    = ws + OFF_XG;
    float* texts = ws + OFF_TEXTS;   // aliased: h0 overwrites texts after xg0 GEMM
    float* h0    = texts;
    float* h1    = ws + OFF_H1;
    float* tok   = ws + OFF_TOK;
    float* emis  = ws + OFF_EMIS;
    float* wpad  = ws + OFF_WPAD;
    float* llh   = ws + OFF_LLH;

    hipMemsetAsync(tok, 0, CDIM * sizeof(float), stream);  // tok_enc row 0 = zeros
    pad_w_k<<<768, 64, 0, stream>>>(w_ih_l0, wpad);
    char_conv_k<<<NW / 8, 256, 0, stream>>>(char_emb, conv_w, conv_b, bcw, tok);
    build_texts_k<<<NPOS, 128, 0, stream>>>(word_emb, tok, btok, bcwi, texts);
    gemm_xg_k<<<dim3(NPOS / GBM, 768 / GBN), 256, 0, stream>>>(texts, wpad, b_ih_l0, xg, IN0P);
    gru_rec_k<<<2 * BATCH, 512, 0, stream>>>(xg, w_hh_l0, b_hh_l0, blen, h0);
    gemm_xg_k<<<dim3(NPOS / GBM, 768 / GBN), 256, 0, stream>>>(h0, w_ih_l1, b_ih_l1, xg, IN1);
    gru_rec_k<<<2 * BATCH, 512, 0, stream>>>(xg, w_hh_l1, b_hh_l1, blen, h1);
    mlp_emis_k<<<NPOS / 8, 128, 0, stream>>>(h1, mlp_w1, mlp_b1, mlp_w2, mlp_b2, emis);
    crf_k<<<BATCH, 64, 0, stream>>>(emis, crf_start, crf_end, crf_trans, target, blen, llh);
    finalize_k<<<1, 64, 0, stream>>>(llh, blen, (float*)d_out);
}